// Round 10
// baseline (856.942 us; speedup 1.0000x reference)
//
#include <hip/hip_runtime.h>
#include <hip/hip_bf16.h>

// DecoderLayer: B=4, T=S=1024, D=1024, H=16, hd=64, F=4096
#define BBATCH 4
#define TT 1024
#define SS 1024
#define DD 1024
#define HH 16
#define HD 64
#define FFD 4096
#define MM (BBATCH*TT)   // 4096 activation rows

using f32x4  = __attribute__((ext_vector_type(4))) float;
using s16x8  = __attribute__((ext_vector_type(8))) short;
using bf16x8 = __attribute__((ext_vector_type(8))) __bf16;

__device__ __forceinline__ unsigned short f2b(float f) {
  union { float f; unsigned int u; } x{f};
  unsigned int r = x.u + 0x7FFFu + ((x.u >> 16) & 1u);
  return (unsigned short)(r >> 16);
}

__device__ __forceinline__ float b2f(unsigned short u) {
  union { unsigned int i; float f; } x; x.i = (unsigned int)u << 16; return x.f;
}

__device__ __forceinline__ void gload16(const void* g, void* l) {
  __builtin_amdgcn_global_load_lds(
      (const __attribute__((address_space(1))) void*)g,
      (__attribute__((address_space(3))) void*)l, 16, 0, 0);
}

__device__ __forceinline__ f32x4 mfma_bf16(s16x8 a, s16x8 b, f32x4 c) {
  return __builtin_amdgcn_mfma_f32_16x16x32_bf16(
      __builtin_bit_cast(bf16x8, a), __builtin_bit_cast(bf16x8, b), c, 0, 0, 0);
}

// XCD-chunked swizzle (T1).  Requires nwg % 8 == 0 (all grids satisfy).
__device__ __forceinline__ void xcd_swz(int gx, int& bn, int& bm) {
  int flat = blockIdx.y * gx + blockIdx.x;
  int nwg = gx * gridDim.y;
  int swz = (flat & 7) * (nwg >> 3) + (flat >> 3);
  bn = swz % gx; bm = swz / gx;
}

// ---------------------------------------------------------------------------
// GEMM core v3: A staged in LDS (dbuf, post-barrier prefetch -- R8/R9 proven),
// B loaded DIRECT global->register, double-buffered one K-step ahead.
// Rationale: the m97-family loop is LDS-read-throughput bound (16 ds_read_b128
// ~192cy vs 32 MFMA ~154cy per step for JT=4); removing B from LDS halves the
// ds_read count (96cy < MFMA).  Named br0/br1 + 2x-unrolled t-loop keeps all
// register-array indexing compile-time (rule #20).  LDS = 32KB (A dbuf only).
// ---------------------------------------------------------------------------
__device__ __forceinline__ void stage_a(
    const unsigned short* __restrict__ Ab, int lda, int kk,
    unsigned short* As, int r0, int c0, int wave)
{
#pragma unroll
  for (int s = 0; s < 2; s++) {
    gload16(Ab + (size_t)r0 * lda + kk + s * 32 + c0, As + s * 4096 + wave * 512);
    gload16(Ab + (size_t)(r0 + 64) * lda + kk + s * 32 + c0, As + s * 4096 + wave * 512 + 2048);
  }
}

// B fragments for one BK=64 step: [sub-tile s][col-tile u], per-lane 16B.
template <int JT>
__device__ __forceinline__ void load_breg(
    const unsigned short* __restrict__ Bl, int ldb, int kk, s16x8 (&br)[2][JT])
{
#pragma unroll
  for (int s = 0; s < 2; s++)
#pragma unroll
    for (int u = 0; u < JT; u++)
      br[s][u] = *(const s16x8*)(Bl + (size_t)u * 16 * ldb + kk + s * 32);
}

template <int JT>
__device__ __forceinline__ void gemm_step(
    const unsigned short* __restrict__ Ab, int lda,
    const unsigned short* __restrict__ Bl, int ldb,
    int t, int nt, unsigned short* AsCur, unsigned short* AsNext,
    s16x8 (&brCur)[2][JT], s16x8 (&brNext)[2][JT],
    f32x4 (&acc)[4][JT], int r0, int c0, int wave, int wrow, int q, int rl)
{
  // Barrier: lgkmcnt(0) -> prior ds_reads of AsCur region done across waves;
  // vmcnt drains stage_a(t)/load_breg(t), issued one full step (~300cy) ago.
  __syncthreads();
  if (t + 1 < nt) {
    stage_a(Ab, lda, (t + 1) << 6, AsNext, r0, c0, wave);
    load_breg<JT>(Bl, ldb, (t + 1) << 6, brNext);
  }
  const s16x8* Av = (const s16x8*)AsCur;
#pragma unroll
  for (int s = 0; s < 2; s++) {
    s16x8 af[4];
#pragma unroll
    for (int u = 0; u < 4; u++) af[u] = Av[s * 512 + (wrow + u * 16 + rl) * 4 + q];
#pragma unroll
    for (int i = 0; i < 4; i++)
#pragma unroll
      for (int j = 0; j < JT; j++)
        acc[i][j] = mfma_bf16(af[i], brCur[s][j], acc[i][j]);
  }
}

// EPI: 0 = Cb=bf16(acc+bias); 2 = Cf=acc+bias+res; 3 = Cb=bf16(relu(acc+bias))
template <int EPI, int JT>
__global__ __launch_bounds__(256) void gemm_bt(
    const unsigned short* __restrict__ A, int lda,
    const unsigned short* __restrict__ B, int ldb,
    const float* __restrict__ bias, const float* __restrict__ res,
    float* __restrict__ Cf, unsigned short* __restrict__ Cb, int ldc, int K)
{
  __shared__ __align__(16) unsigned short As[2 * 8192];   // 32KB A dbuf
  int bm, bn;
  xcd_swz(gridDim.x, bn, bm);
  const int tid = threadIdx.x;
  const int lane = tid & 63, wave = tid >> 6;
  const int wrow = (wave >> 1) * 64, wcol = (wave & 1) * 16 * JT;
  const int q = lane >> 4, rl = lane & 15;
  const int r0 = tid >> 2, c0 = (tid & 3) * 8;

  const unsigned short* Ab = A + (size_t)bm * 128 * lda;
  const unsigned short* Bl = B + (size_t)(bn * (32 * JT) + wcol + rl) * ldb + q * 8;

  f32x4 acc[4][JT];
  f32x4 z = {0.f, 0.f, 0.f, 0.f};
#pragma unroll
  for (int i = 0; i < 4; i++)
#pragma unroll
    for (int j = 0; j < JT; j++) acc[i][j] = z;

  s16x8 br0[2][JT], br1[2][JT];
  stage_a(Ab, lda, 0, As, r0, c0, wave);
  load_breg<JT>(Bl, ldb, 0, br0);
  const int nt = K >> 6;   // always even (16 or 64)
  for (int t = 0; t < nt; t += 2) {
    gemm_step<JT>(Ab, lda, Bl, ldb, t, nt, As, As + 8192, br0, br1,
                  acc, r0, c0, wave, wrow, q, rl);
    gemm_step<JT>(Ab, lda, Bl, ldb, t + 1, nt, As + 8192, As, br1, br0,
                  acc, r0, c0, wave, wrow, q, rl);
  }

#pragma unroll
  for (int i = 0; i < 4; i++) {
    int gm0 = bm * 128 + wrow + i * 16 + q * 4;
#pragma unroll
    for (int j = 0; j < JT; j++) {
      int gn = bn * (32 * JT) + wcol + j * 16 + rl;
      float bv = bias[gn];
#pragma unroll
      for (int r = 0; r < 4; r++) {
        size_t off = (size_t)(gm0 + r) * ldc + gn;
        float v = acc[i][j][r];
        if constexpr (EPI == 0) Cb[off] = f2b(v + bv);
        else if constexpr (EPI == 2) Cf[off] = v + bv + res[off];
        else Cb[off] = f2b(fmaxf(v + bv, 0.f));
      }
    }
  }
}

// ---------------------------------------------------------------------------
// FUSED QKV(self) + KV(cross) projection GEMM.  grid (40, 32):
//   bn 0..23  : A=Xb, W=Wq1|Wk1|Wv1, out QKVb  (bn 16..23 = V -> Vt1 direct)
//   bn 24..39 : A=Eb, W=Wk2|Wv2,     out KVb   (b2  8..15 = V -> Vt2 direct)
// V-range blocks emit V^T from the epilogue via the dead A-staging LDS.
// ---------------------------------------------------------------------------
__global__ __launch_bounds__(256) void gemm_qkvkv(
    const unsigned short* __restrict__ Xb, const unsigned short* __restrict__ Eb,
    const unsigned short* __restrict__ Wqkv1, const unsigned short* __restrict__ Wkv2,
    const float* __restrict__ bqkv, const float* __restrict__ bkv,
    unsigned short* __restrict__ QKVb, unsigned short* __restrict__ KVb,
    unsigned short* __restrict__ Vt1, unsigned short* __restrict__ Vt2)
{
  __shared__ __align__(16) unsigned short lds[2 * 8192];   // 32KB A dbuf / transpose tile
  const int tid = threadIdx.x;
  int bm, bn;
  xcd_swz(gridDim.x, bn, bm);
  const int lane = tid & 63, wave = tid >> 6;
  const int wrow = (wave >> 1) * 64, wcol = (wave & 1) * 64;
  const int q = lane >> 4, rl = lane & 15;
  const int r0 = tid >> 2, c0 = (tid & 3) * 8;

  const unsigned short *A, *Bw;
  const float* bias;
  unsigned short *C, *Vt;
  int ldc, vbn;
  bool isV;
  if (bn < 24) {
    A = Xb; Bw = Wqkv1 + (size_t)bn * 128 * 1024; bias = bqkv + bn * 128;
    C = QKVb + bn * 128; ldc = 3072;
    isV = (bn >= 16); Vt = Vt1; vbn = bn - 16;
  } else {
    int b2 = bn - 24;
    A = Eb; Bw = Wkv2 + (size_t)b2 * 128 * 1024; bias = bkv + b2 * 128;
    C = KVb + b2 * 128; ldc = 2048;
    isV = (b2 >= 8); Vt = Vt2; vbn = b2 - 8;
  }
  const unsigned short* Ab = A + (size_t)bm * 128 * 1024;
  const unsigned short* Bl = Bw + (size_t)(wcol + rl) * 1024 + q * 8;

  f32x4 acc[4][4];
  f32x4 z = {0.f, 0.f, 0.f, 0.f};
#pragma unroll
  for (int i = 0; i < 4; i++)
#pragma unroll
    for (int j = 0; j < 4; j++) acc[i][j] = z;

  s16x8 br0[2][4], br1[2][4];
  stage_a(Ab, 1024, 0, lds, r0, c0, wave);
  load_breg<4>(Bl, 1024, 0, br0);
  for (int t = 0; t < 16; t += 2) {
    gemm_step<4>(Ab, 1024, Bl, 1024, t, 16, lds, lds + 8192, br0, br1,
                 acc, r0, c0, wave, wrow, q, rl);
    gemm_step<4>(Ab, 1024, Bl, 1024, t + 1, 16, lds + 8192, lds, br1, br0,
                 acc, r0, c0, wave, wrow, q, rl);
  }

  if (!isV) {
#pragma unroll
    for (int i = 0; i < 4; i++) {
      int lr0 = wrow + i * 16 + q * 4;
#pragma unroll
      for (int j = 0; j < 4; j++) {
        int lc = wcol + j * 16 + rl;
        float bv = bias[lc];
#pragma unroll
        for (int r = 0; r < 4; r++)
          C[(size_t)(bm * 128 + lr0 + r) * ldc + lc] = f2b(acc[i][j][r] + bv);
      }
    }
  } else {
    __syncthreads();   // final ds_reads of lds done across all waves
    // transpose via LDS: lds[lc*128 + (lr ^ ((lc&7)<<2))] = tile[lr][lc]
#pragma unroll
    for (int i = 0; i < 4; i++) {
      int lr0 = wrow + i * 16 + q * 4;
#pragma unroll
      for (int j = 0; j < 4; j++) {
        int lc = wcol + j * 16 + rl;
        float bv = bias[lc];
        int base = lc * 128, sw = (lc & 7) << 2;
#pragma unroll
        for (int r = 0; r < 4; r++)
          lds[base + ((lr0 + r) ^ sw)] = f2b(acc[i][j][r] + bv);
      }
    }
    __syncthreads();
    const int b = bm >> 3, s0 = (bm & 7) * 128;
#pragma unroll
    for (int it = 0; it < 16; it++) {
      int idx = it * 256 + tid;              // 4096 quads = 128 lc x 32 qa
      int lc = idx >> 5, qa = idx & 31;
      ushort4 v4 = *(const ushort4*)&lds[lc * 128 + ((qa ^ (lc & 7)) << 2)];
      int h = vbn * 2 + (lc >> 6), d = lc & 63;
      *(ushort4*)&Vt[(((size_t)b * 16 + h) * 64 + d) * 1024 + s0 + qa * 4] = v4;
    }
  }
}

// ---------------------------------------------------------------------------
// Flash building blocks.
// ---------------------------------------------------------------------------
__device__ __forceinline__ void stage_k(
    const unsigned short* src, int ldk, unsigned short* Kbuf,
    int r0, int c0, int wave)
{
#pragma unroll
  for (int kq = 0; kq < 2; kq++) {
    gload16(src + (size_t)r0 * ldk + kq * 32 + c0, Kbuf + kq * 4096 + wave * 512);
    gload16(src + (size_t)(r0 + 64) * ldk + kq * 32 + c0, Kbuf + kq * 4096 + wave * 512 + 2048);
  }
}

__device__ __forceinline__ void sblock_qk(
    const unsigned short* Qs, const unsigned short* Ks,
    int wrow, int wcol, int q, int rl, f32x4 (&acc)[4][4])
{
  const s16x8* Qv = (const s16x8*)Qs;
  const s16x8* Kv = (const s16x8*)Ks;
  f32x4 z = {0.f, 0.f, 0.f, 0.f};
#pragma unroll
  for (int i = 0; i < 4; i++)
#pragma unroll
    for (int j = 0; j < 4; j++) acc[i][j] = z;
#pragma unroll
  for (int kq = 0; kq < 2; kq++) {
    s16x8 af[4], bf[4];
#pragma unroll
    for (int t = 0; t < 4; t++) af[t] = Qv[kq * 512 + (wrow + t * 16 + rl) * 4 + q];
#pragma unroll
    for (int t = 0; t < 4; t++) bf[t] = Kv[kq * 512 + (wcol + t * 16 + rl) * 4 + q];
#pragma unroll
    for (int i = 0; i < 4; i++)
#pragma unroll
      for (int j = 0; j < 4; j++)
        acc[i][j] = mfma_bf16(af[i], bf[j], acc[i][j]);
  }
}

// V fragments directly from global (Vt is L2-resident).
__device__ __forceinline__ void load_vf(
    const unsigned short* Vbase, int c, int wc2, int q, int rl, s16x8 (&vf)[4][2])
{
#pragma unroll
  for (int ks = 0; ks < 4; ks++)
#pragma unroll
    for (int t = 0; t < 2; t++)
      vf[ks][t] = *(const s16x8*)(Vbase + (size_t)(wc2 + t * 16 + rl) * SS +
                                  c * 128 + ks * 32 + q * 8);
}

// P store into the swizzled standalone Ps tile ([4][128][32] u16, 16B-unit
// XOR swizzle: unit = (row*4 + u) ^ ((row>>1)&3)).
__device__ __forceinline__ void store_ps_swz(
    unsigned short* Ps, const f32x4 (&acc)[4][4], int wrow, int wcol, int q, int rl)
{
#pragma unroll
  for (int i = 0; i < 4; i++)
#pragma unroll
    for (int j = 0; j < 4; j++) {
      int col = wcol + j * 16 + rl;
      int ks = col >> 5, cc = col & 31;
#pragma unroll
      for (int r = 0; r < 4; r++) {
        int row = wrow + i * 16 + q * 4 + r;
        int unit = (row * 4 + (cc >> 3)) ^ ((row >> 1) & 3);
        Ps[ks * 4096 + unit * 8 + (cc & 7)] = f2b(acc[i][j][r]);
      }
    }
}

__device__ __forceinline__ void pv_swz(
    const unsigned short* Ps, const s16x8 (&vf)[4][2],
    int wrow, int q, int rl, f32x4 (&oacc)[4][2])
{
  const s16x8* Pv = (const s16x8*)Ps;
#pragma unroll
  for (int ks = 0; ks < 4; ks++) {
    s16x8 af[4];
#pragma unroll
    for (int t = 0; t < 4; t++) {
      int row = wrow + t * 16 + rl;
      af[t] = Pv[ks * 512 + ((row * 4 + q) ^ ((row >> 1) & 3))];
    }
#pragma unroll
    for (int i = 0; i < 4; i++)
#pragma unroll
      for (int jt = 0; jt < 2; jt++)
        oacc[i][jt] = mfma_bf16(af[i], vf[ks][jt], oacc[i][jt]);
  }
}

// ---------------------------------------------------------------------------
// NO-MAX flash attention, post-barrier staging + K double-buffer.
// 2 barriers/chunk; V direct-from-global.  LDS 80KB -> 2 blocks/CU.
// ---------------------------------------------------------------------------
__global__ __launch_bounds__(256, 2) void flash_sa(
    const unsigned short* __restrict__ Qg, int ldq,
    const unsigned short* __restrict__ Kg, int ldk,
    const unsigned short* __restrict__ Vt,     // [bh][64][1024]
    unsigned short* __restrict__ Og)           // [4096][1024]
{
  __shared__ __align__(16) unsigned short Qs[2 * 128 * 32];       // 16KB
  __shared__ __align__(16) unsigned short Ks[2][2 * 128 * 32];    // 32KB dbuf
  __shared__ __align__(16) unsigned short Ps[4 * 128 * 32];       // 32KB swizzled

  const int tid = threadIdx.x, wave = tid >> 6, lane = tid & 63;
  const int q = lane >> 4, rl = lane & 15;
  const int bh = blockIdx.y, b = bh >> 4, h = bh & 15;
  const int bm = (bh & 32) ? (7 - blockIdx.x) : blockIdx.x;   // causal balance
  const int wrow = (wave >> 1) * 64, wcol = (wave & 1) * 64;
  const int wc2 = (wave & 1) * 32;
  const int r0 = tid >> 2, c0 = (tid & 3) * 8;

  const unsigned short* Qbase = Qg + ((size_t)b * TT + bm * 128) * ldq + h * HD;
  const unsigned short* Kbase = Kg + (size_t)b * SS * ldk + h * HD;
  const unsigned short* Vbase = Vt + ((size_t)bh << 16);

#pragma unroll
  for (int kq = 0; kq < 2; kq++) {
    gload16(Qbase + (size_t)r0 * ldq + kq * 32 + c0, Qs + kq * 4096 + wave * 512);
    gload16(Qbase + (size_t)(r0 + 64) * ldq + kq * 32 + c0, Qs + kq * 4096 + wave * 512 + 2048);
  }
  stage_k(Kbase, ldk, Ks[0], r0, c0, wave);
  const int nch = bm + 1;

  float l_run[4][4];
  f32x4 oacc[4][2];
  f32x4 z = {0.f, 0.f, 0.f, 0.f};
#pragma unroll
  for (int i = 0; i < 4; i++) {
    oacc[i][0] = z; oacc[i][1] = z;
#pragma unroll
    for (int r = 0; r < 4; r++) l_run[i][r] = 0.f;
  }

  for (int c = 0; c < nch; c++) {
    __syncthreads();   // B_a: drains stage(c); syncs PV(c-1) -> K[c^1] & Ps free
    if (c + 1 < nch)
      stage_k(Kbase + (size_t)(c + 1) * 128 * ldk, ldk, Ks[(c + 1) & 1], r0, c0, wave);
    s16x8 vf[4][2];
    load_vf(Vbase, c, wc2, q, rl, vf);
    f32x4 acc[4][4];
    sblock_qk(Qs, Ks[c & 1], wrow, wcol, q, rl, acc);
    // P' = exp(s/8) (no max-sub; masked -> 0), accumulate wave-partial l
#pragma unroll
    for (int i = 0; i < 4; i++)
#pragma unroll
      for (int r = 0; r < 4; r++) {
#pragma unroll
        for (int j = 0; j < 4; j++) {
          float v = acc[i][j][r] * 0.125f;
          bool msk = (c == bm) && (wcol + j * 16 + rl) > (wrow + i * 16 + q * 4 + r);
          acc[i][j][r] = msk ? 0.f : __expf(v);
        }
        float s = acc[i][0][r] + acc[i][1][r] + acc[i][2][r] + acc[i][3][r];
#pragma unroll
        for (int off = 1; off < 16; off <<= 1) s += __shfl_xor(s, off);
        l_run[i][r] += s;
      }
    store_ps_swz(Ps, acc, wrow, wcol, q, rl);
    __syncthreads();   // B_b: Ps visible
    pv_swz(Ps, vf, wrow, q, rl, oacc);
  }
  __syncthreads();     // last PV reads of Ps done before reuse as red

  float* red = (float*)Ps;
  if (rl == 0) {
#pragma unroll
    for (int i = 0; i < 4; i++)
#pragma unroll
      for (int r = 0; r < 4; r++)
        red[(wave & 1) * 128 + wrow + i * 16 + q * 4 + r] = l_run[i][r];
  }
  __syncthreads();

#pragma unroll
  for (int i = 0; i < 4; i++) {
#pragma unroll
    for (int r = 0; r < 4; r++) {
      int row = wrow + i * 16 + q * 4 + r;
      float inv = 1.0f / (red[row] + red[128 + row]);
      int grow = bm * 128 + row;
#pragma unroll
      for (int jt = 0; jt < 2; jt++) {
        int col = h * HD + wc2 + jt * 16 + rl;
        Og[((size_t)b * TT + grow) * DD + col] = f2b(oacc[i][jt][r] * inv);
      }
    }
  }
}

// ---------------------------------------------------------------------------
// NO-MAX two-phase flash attention (cross-attn, fp32 P output).
// Phase A: post-barrier staged K dbuf -> 1 barrier/chunk.
// Phase B: 2 barriers/chunk; V direct; Pout via vectorized LDS readback.
// ---------------------------------------------------------------------------
__global__ __launch_bounds__(256, 2) void flash_ca(
    const unsigned short* __restrict__ Qg, int ldq,
    const unsigned short* __restrict__ Kg, int ldk,
    const unsigned short* __restrict__ Vt,     // [bh][64][1024]
    float* __restrict__ Pout,                  // [bh][1024][1024]
    unsigned short* __restrict__ Og)           // [4096][1024]
{
  __shared__ __align__(16) unsigned short Qs[2 * 128 * 32];
  __shared__ __align__(16) unsigned short Ks[2][2 * 128 * 32];
  __shared__ __align__(16) unsigned short Ps[4 * 128 * 32];

  const int tid = threadIdx.x, wave = tid >> 6, lane = tid & 63;
  const int q = lane >> 4, rl = lane & 15;
  const int bm = blockIdx.x, bh = blockIdx.y, b = bh >> 4, h = bh & 15;
  const int wrow = (wave >> 1) * 64, wcol = (wave & 1) * 64;
  const int wc2 = (wave & 1) * 32;
  const int r0 = tid >> 2, c0 = (tid & 3) * 8;

  const unsigned short* Qbase = Qg + ((size_t)b * TT + bm * 128) * ldq + h * HD;
  const unsigned short* Kbase = Kg + (size_t)b * SS * ldk + h * HD;
  const unsigned short* Vbase = Vt + ((size_t)bh << 16);

#pragma unroll
  for (int kq = 0; kq < 2; kq++) {
    gload16(Qbase + (size_t)r0 * ldq + kq * 32 + c0, Qs + kq * 4096 + wave * 512);
    gload16(Qbase + (size_t)(r0 + 64) * ldq + kq * 32 + c0, Qs + kq * 4096 + wave * 512 + 2048);
  }
  stage_k(Kbase, ldk, Ks[0], r0, c0, wave);

  float l_run[4][4];
#pragma unroll
  for (int i = 0; i < 4; i++)
#pragma unroll
    for (int r = 0; r < 4; r++) l_run[i][r] = 0.f;

  // ---------------- Phase A: denominators only (1 barrier/chunk) ----------
  for (int c = 0; c < 8; c++) {
    __syncthreads();   // drains stage(c) (a full chunk old for c>0)
    if (c < 7)
      stage_k(Kbase + (size_t)(c + 1) * 128 * ldk, ldk, Ks[(c + 1) & 1], r0, c0, wave);
    f32x4 acc[4][4];
    sblock_qk(Qs, Ks[c & 1], wrow, wcol, q, rl, acc);
#pragma unroll
    for (int i = 0; i < 4; i++)
#pragma unroll
      for (int r = 0; r < 4; r++) {
        float s = __expf(acc[i][0][r] * 0.125f) + __expf(acc[i][1][r] * 0.125f) +
                  __expf(acc[i][2][r] * 0.125f) + __expf(acc[i][3][r] * 0.125f);
#pragma unroll
        for (int off = 1; off < 16; off <<= 1) s += __shfl_xor(s, off);
        l_run[i][r] += s;
      }
  }
  float* red = (float*)Ps;   // Ps untouched in phase A
  if (rl == 0) {
#pragma unroll
    for (int i = 0; i < 4; i++)
#pragma unroll
      for (int r = 0; r < 4; r++)
        red[(wave & 1) * 128 + wrow + i * 16 + q * 4 + r] = l_run[i][r];
  }
  __syncthreads();
  float invl[4][4];
#pragma unroll
  for (int i = 0; i < 4; i++)
#pragma unroll
    for (int r = 0; r < 4; r++) {
      int row = wrow + i * 16 + q * 4 + r;
      invl[i][r] = 1.0f / (red[row] + red[128 + row]);
    }

  // ---------------- Phase B: P + PV (2 barriers/chunk) ----------
  f32x4 oacc[4][2];
  f32x4 z = {0.f, 0.f, 0.f, 0.f};
#pragma unroll
  for (int i = 0; i < 4; i++) { oacc[i][0] = z; oacc[i][1] = z; }
  stage_k(Kbase, ldk, Ks[0], r0, c0, wave);   // all waves past invl barrier

  for (int c = 0; c < 8; c++) {
    __syncthreads();   // B_a: drains stage(c); PV(c-1)/red reads done
    if (c < 7)
      stage_k(Kbase + (size_t)(c + 1) * 128 * ldk, ldk, Ks[(c + 1) & 1], r0, c0, wave);
    s16x8 vf[4][2];
    load_vf(Vbase, c, wc2, q, rl, vf);
    f32x4 acc[4][4];
    sblock_qk(Qs, Ks[c & 1], wrow, wcol, q, rl, acc);
#pragma unroll
    for (int i = 0; i < 4; i++)
#pragma unroll
      for (int j = 0; j < 4; j++)
#pragma unroll
        for (int r = 0; r < 4; r++)
          acc[i][j][r] = __expf(acc[i][j][r] * 0.125f) * invl[i][r];
    store_ps_swz(Ps, acc, wrow, wcol, q, rl);
    __syncthreads();   // B_b: Ps visible
    // P -> global, vectorized from LDS (bf16 -> 2x float4, 128B-coalesced)
#pragma unroll
    for (int it = 0; it < 8; it++) {
      int idx = it * 256 + tid;                  // [0,2048)
      int ks = idx >> 9, rw = (idx >> 2) & 127, u = idx & 3;
      s16x8 pv = ((const s16x8*)Ps)[ks * 512 + ((rw * 4 + u) ^ ((rw >> 1) & 3))];
      float4 lo = make_float4(b2f((unsigned short)pv[0]), b2f((unsigned short)pv[1]),
                              b2f((unsigned short)pv[2]), b2f((unsigned short)pv[3]));
      float4 hi = make_float4(b2f((unsigned short)pv[4]), b2f((unsigned short)pv[5]),
                              b2f((unsigned short)pv[6]), b2f((unsigned short)pv[7]));
      float* dst = Pout + ((size_t)bh << 20) + ((size_t)(bm * 128 + rw) << 10) +
                   c * 128 + ks * 32 + u * 8;
      ((float4*)dst)[0] = lo;
      ((float4*)dst)[1] = hi;
    }
    pv_swz(Ps, vf, wrow, q, rl, oacc);
  }

#pragma unroll
  for (int i = 0; i < 4; i++)
#pragma unroll
    for (int jt = 0; jt < 2; jt++)
#pragma unroll
      for (int r = 0; r < 4; r++) {
        int row = bm * 128 + wrow + i * 16 + q * 4 + r;
        int col = h * HD + wc2 + jt * 16 + rl;
        Og[((size_t)b * TT + row) * DD + col] = f2b(oacc[i][jt][r]);
      }
}

__global__ __launch_bounds__(256) void ln_k(
    const float* __restrict__ src, const float* __restrict__ g,
    const float* __restrict__ b, float* __restrict__ dstf,
    unsigned short* __restrict__ dstb)
{
  __shared__ float sh[10];
  const size_t row = blockIdx.x;
  const int tid = threadIdx.x;
  float4 v = ((const float4*)(src + (row << 10)))[tid];
  float s = v.x + v.y + v.z + v.w;
  float ss = v.x * v.x + v.y * v.y + v.z * v.z + v.w * v.w;
  for (int o = 32; o; o >>= 1) { s += __shfl_down(s, o); ss += __shfl_down(ss, o); }
  if ((tid & 63) == 0) { sh[tid >> 6] = s; sh[4 + (tid >> 6)] = ss; }
  __syncthreads();
  if (tid == 0) {
    sh[8] = sh[0] + sh[1] + sh[2] + sh[3];
    sh[9] = sh[4] + sh[5] + sh[6] + sh[7];
  }
  __syncthreads();
  const float mean = sh[8] * (1.0f / DD);
  const float var = sh[9] * (1.0f / DD) - mean * mean;
  const float inv = rsqrtf(var + 1e-5f);
  float4 gv = ((const float4*)g)[tid];
  float4 bv = ((const float4*)b)[tid];
  float4 y;
  y.x = (v.x - mean) * inv * gv.x + bv.x;
  y.y = (v.y - mean) * inv * gv.y + bv.y;
  y.z = (v.z - mean) * inv * gv.z + bv.z;
  y.w = (v.w - mean) * inv * gv.w + bv.w;
  if (dstf) ((float4*)(dstf + (row << 10)))[tid] = y;
  if (dstb) {
    ushort4 o = make_ushort4(f2b(y.x), f2b(y.y), f2b(y.z), f2b(y.w));
    ((ushort4*)(dstb + (row << 10)))[tid] = o;
  }
}

// ---------------------------------------------------------------------------
// Fused fp32 -> bf16 conversion of ALL inputs + bias packing in one launch.
// ---------------------------------------------------------------------------
struct CvtArgs {
  const float* src[12];
  unsigned short* dst[12];
  const float *bq, *bk, *bv, *bk2, *bv2;
  float *bqkv, *bkv;
};

__global__ __launch_bounds__(256) void cvt_all(CvtArgs a) {
  const int blk = blockIdx.x;
  if (blk >= 24576) {   // bias packing tail (20 blocks)
    int i = (blk - 24576) * 256 + threadIdx.x;
    if (i < 1024) a.bqkv[i] = a.bq[i];
    else if (i < 2048) a.bqkv[i] = a.bk[i - 1024];
    else if (i < 3072) a.bqkv[i] = a.bv[i - 2048];
    else if (i < 4096) a.bkv[i - 3072] = a.bk2[i - 3072];
    else if (i < 5120) a.bkv[i - 3072] = a.bv2[i - 4096 + 1024];
    return;
  }
  // f4 units: tgt(1M) enc(1M) 8x weights(256K) ff_w1(1M) ff_w2(1M)
  constexpr int st[13] = {0,       1048576, 2097152, 2359296, 2621440,
                          2883584, 3145728, 3407872, 3670016, 3932160,
                          4194304, 5242880, 6291456};
  int i = blk * 256 + threadIdx.x;
  int s = 0;
#pragma unroll
  for (int k = 1; k < 12; k++) s += (i >= st[k]) ? 1 : 0;
  int j = i - st[s];
  float4 v = ((const float4*)a.src[s])[j];
  ushort4 o = make_ushort4(f2b(v.x), f2b(v.y), f2b(v.z), f2b(v.w));
  ((ushort4*)a.dst[s])[j] = o;
}

// ---------------------------------------------------------------------------

extern "C" void kernel_launch(void* const* d_in, const int* in_sizes, int n_in,
                              void* d_out, int out_size, void* d_ws, size_t ws_size,
                              hipStream_t stream)
{
  const float* tgt = (const float*)d_in[0];
  const float* enc = (const float*)d_in[1];
  const float* sa_wq = (const float*)d_in[4];  const float* sa_bq = (const float*)d_in[5];
  const float* sa_wk = (const float*)d_in[6];  const float* sa_bk = (const float*)d_in[7];
  const float* sa_wv = (const float*)d_in[8];  const float* sa_bv = (const float*)d_in[9];
  const float* sa_wo = (const float*)d_in[10]; const float* sa_bo = (const float*)d_in[11];
  const float* ca_wq = (const float*)d_in[12]; const float* ca_bq = (const float*)d_in[13];
  const float* ca_wk = (const float*)d_in[14]; const float* ca_bk = (const float*)d_in[15];
  const float* ca_wv = (const float*)d_in[16]; const float* ca_bv = (const float*)d_in[17];
  const float* ca_wo = (const float*)d_in[18]; const float* ca_bo = (const float*)d_in[19];
  const float* ff_w1 = (const float*)d_in[20]; const float* ff_b1 = (const float*)d_in[21];
  const float* ff_w2 = (const float*)d_in[22]; const float* ff_b2 = (const float*)d_in[23];
  const float* ln1_g = (const float*)d_in[24]; const float* ln1_b = (const float*)d_in[25];
  const float* ln2_g = (const float*)d_in[26]; const float* ln2_b = (const float*)d_in[27];
  const float* ln3_g = (const float*)d_in[28]; const float* ln3_b = (const float*)d_in[29];

  float* out_tgt = (float*)d_out;
  float* out_attn = (float*)d_out + (size_t)MM * DD;

  char* w = (char*)d_ws;
  size_t off = 0;
  auto alloc = [&](size_t bytes) { void* p = w + off; off += (bytes + 255) & ~(size_t)255; return p; };
  unsigned short* Xb   = (unsigned short*)alloc((size_t)MM * DD * 2);
  unsigned short* Eb   = (unsigned short*)alloc((size_t)MM * DD * 2);
  unsigned short* Wq1  = (unsigned short*)alloc((size_t)DD * DD * 2);  // Wq1|Wk1|Wv1 contiguous
  unsigned short* Wk1  = (unsigned short*)alloc((size_t)DD * DD * 2);
  unsigned short* Wv1  = (unsigned short*)alloc((size_t)DD * DD * 2);
  unsigned short* Wo1  = (unsigned short*)alloc((size_t)DD * DD * 2);
  unsigned short* Wq2  = (unsigned short*)alloc((size_t)DD * DD * 2);
  unsigned short* Wk2  = (unsigned short*)alloc((size_t)DD * DD * 2);  // Wk2|Wv2 contiguous
  unsigned short* Wv2  = (unsigned short*)alloc((size_t)DD * DD * 2);
  unsigned short* Wo2  = (unsigned short*)alloc((size_t)DD * DD * 2);
  unsigned short* Wf1  = (unsigned short*)alloc((size_t)FFD * DD * 2);
  unsigned short* Wf2  = (unsigned short*)alloc((size_t)DD * FFD * 2);
  unsigned short* QKVb = (unsigned short*)alloc((size_t)MM * 3 * DD * 2); // [4096][3072]
  unsigned short* KVb  = (unsigned short*)alloc((size_t)MM * 2 * DD * 2); // [4096][2048]
  unsigned short* Qca  = (unsigned short*)alloc((size_t)MM * DD * 2);
  unsigned short* Vt1  = (unsigned short*)alloc((size_t)MM * DD * 2);
  unsigned short* Vt2  = (unsigned short*)alloc((size_t)MM * DD * 2);
  unsigned short* Ob   = (unsigned short*)alloc((size_t)MM * DD * 2);
  float*          res1 = (float*)alloc((size_t)MM * DD * 4);
  unsigned short* t1b  = (unsigned short*)alloc((size_t)MM * DD * 2);
  float*          res2 = (float*)alloc((size_t)MM * DD * 4);
  unsigned short* t2b  = (unsigned short*)alloc((size_t)MM * DD * 2);
  unsigned short* Fb   = (unsigned short*)alloc((size_t)MM * FFD * 2);
  float*          bqkv = (float*)alloc(3072 * 4);
  float*          bkv  = (float*)alloc(2048 * 4);

  CvtArgs ca;
  ca.src[0] = tgt;   ca.dst[0] = Xb;
  ca.src[1] = enc;   ca.dst[1] = Eb;
  ca.src[2] = sa_wq; ca.dst[2] = Wq1;
  ca.src[3] = sa_wk; ca.dst[3] = Wk1;
  ca.src[4] = sa_wv; ca.dst[4] = Wv1;
  ca.src[5] = sa_wo; ca.dst[5] = Wo1;
  ca.src[6] = ca_wq; ca.dst[6] = Wq2;
  ca.src[7] = ca_wk; ca.dst[7] = Wk2;
  ca.src[8] = ca_wv; ca.dst[8] = Wv2;
  ca.src[9] = ca_wo; ca.dst[9] = Wo2;
  ca.src[10] = ff_w1; ca.dst[10] = Wf1;
  ca.src[11] = ff_w2; ca.dst[11] = Wf2;
  ca.bq = sa_bq; ca.bk = sa_bk; ca.bv = sa_bv; ca.bk2 = ca_bk; ca.bv2 = ca_bv;
  ca.bqkv = bqkv; ca.bkv = bkv;

  cvt_all<<<24596, 256, 0, stream>>>(ca);

  const dim3 gPRJ(40, 32);           // fused QKV(24) + KV(16) column-tiles
  const dim3 gN64(16, 32);           // N=1024, 64-tiles (512 blocks)
  const dim3 gFF1(32, 32);           // N=4096, 128-tiles
  const dim3 gFl(8, 64);

  // ---- Projections (self QKV + cross KV, V^T emitted directly) ----
  gemm_qkvkv<<<gPRJ, 256, 0, stream>>>(Xb, Eb, Wq1, Wk2, bqkv, bkv,
                                       QKVb, KVb, Vt1, Vt2);

  // ---- Self-attention ----
  flash_sa<<<gFl, 256, 0, stream>>>(QKVb, 3 * DD, QKVb + DD, 3 * DD, Vt1, Ob);
  gemm_bt<2, 2><<<gN64, 256, 0, stream>>>(Ob, DD, Wo1, DD, sa_bo, tgt, res1, nullptr, DD, DD);
  ln_k<<<MM, 256, 0, stream>>>(res1, ln1_g, ln1_b, res1, t1b);

  // ---- Cross-attention ----
  gemm_bt<0, 2><<<gN64, 256, 0, stream>>>(t1b, DD, Wq2, DD, ca_bq, nullptr, nullptr, Qca, DD, DD);
  flash_ca<<<gFl, 256, 0, stream>>>(Qca, DD, KVb, 2 * DD, Vt2, out_attn, Ob);
  gemm_bt<2, 2><<<gN64, 256, 0, stream>>>(Ob, DD, Wo2, DD, ca_bo, res1, res2, nullptr, DD, DD);
  ln_k<<<MM, 256, 0, stream>>>(res2, ln2_g, ln2_b, res2, t2b);

  // ---- Feed-forward ----
  gemm_bt<3, 4><<<gFF1, 256, 0, stream>>>(t2b, DD, Wf1, DD, ff_b1, nullptr, nullptr, Fb, FFD, DD);
  gemm_bt<2, 2><<<gN64, 256, 0, stream>>>(Fb, FFD, Wf2, FFD, ff_b2, res2, res1, nullptr, DD, FFD);
  ln_k<<<MM, 256, 0, stream>>>(res1, ln3_g, ln3_b, out_tgt, nullptr);
}

// Round 11
// 760.134 us; speedup vs baseline: 1.1274x; 1.1274x over previous
//
#include <hip/hip_runtime.h>
#include <hip/hip_bf16.h>

// DecoderLayer: B=4, T=S=1024, D=1024, H=16, hd=64, F=4096
#define BBATCH 4
#define TT 1024
#define SS 1024
#define DD 1024
#define HH 16
#define HD 64
#define FFD 4096
#define MM (BBATCH*TT)   // 4096 activation rows

using f32x4  = __attribute__((ext_vector_type(4))) float;
using s16x8  = __attribute__((ext_vector_type(8))) short;
using bf16x8 = __attribute__((ext_vector_type(8))) __bf16;

__device__ __forceinline__ unsigned short f2b(float f) {
  union { float f; unsigned int u; } x{f};
  unsigned int r = x.u + 0x7FFFu + ((x.u >> 16) & 1u);
  return (unsigned short)(r >> 16);
}

__device__ __forceinline__ float b2f(unsigned short u) {
  union { unsigned int i; float f; } x; x.i = (unsigned int)u << 16; return x.f;
}

__device__ __forceinline__ void gload16(const void* g, void* l) {
  __builtin_amdgcn_global_load_lds(
      (const __attribute__((address_space(1))) void*)g,
      (__attribute__((address_space(3))) void*)l, 16, 0, 0);
}

__device__ __forceinline__ f32x4 mfma_bf16(s16x8 a, s16x8 b, f32x4 c) {
  return __builtin_amdgcn_mfma_f32_16x16x32_bf16(
      __builtin_bit_cast(bf16x8, a), __builtin_bit_cast(bf16x8, b), c, 0, 0, 0);
}

// XCD-chunked swizzle (T1).  Requires nwg % 8 == 0 (all grids satisfy).
__device__ __forceinline__ void xcd_swz(int gx, int& bn, int& bm) {
  int flat = blockIdx.y * gx + blockIdx.x;
  int nwg = gx * gridDim.y;
  int swz = (flat & 7) * (nwg >> 3) + (flat >> 3);
  bn = swz % gx; bm = swz / gx;
}

// ---------------------------------------------------------------------------
// GEMM core (R8 flash pattern applied): double-buffered LDS, prefetch issued
// POST-barrier so the next barrier's implicit vmcnt(0) only drains loads that
// are a full compute-phase (~300cy) old.  ONE barrier per BK=64 step.
// LDS: JT=4 -> 64KB (2 blocks/CU), JT=2 -> 48KB.
// ---------------------------------------------------------------------------
template <int JT>
__device__ __forceinline__ void stage_ab(
    const unsigned short* __restrict__ Ab, int lda,
    const unsigned short* __restrict__ Bb, int ldb,
    int kk, unsigned short* As, unsigned short* Bs, int r0, int c0, int wave)
{
#pragma unroll
  for (int s = 0; s < 2; s++) {
    int k2 = kk + s * 32;
    gload16(Ab + (size_t)r0 * lda + k2 + c0, As + s * 4096 + wave * 512);
    gload16(Ab + (size_t)(r0 + 64) * lda + k2 + c0, As + s * 4096 + wave * 512 + 2048);
    gload16(Bb + (size_t)r0 * ldb + k2 + c0, Bs + s * (JT * 1024) + wave * 512);
    if (JT == 4)
      gload16(Bb + (size_t)(r0 + 64) * ldb + k2 + c0, Bs + s * (JT * 1024) + wave * 512 + 2048);
  }
}

template <int JT>
__device__ __forceinline__ void gemm_core_db(
    const unsigned short* __restrict__ Ab, int lda,
    const unsigned short* __restrict__ Bb, int ldb,
    int K, unsigned short* As, unsigned short* Bs, f32x4 (&acc)[4][JT])
{
  const int tid = threadIdx.x, wave = tid >> 6, lane = tid & 63;
  const int r0 = tid >> 2, c0 = (tid & 3) * 8;
  const int wrow = (wave >> 1) * 64, wcol = (wave & 1) * 16 * JT;
  const int q = lane >> 4, rl = lane & 15;

  stage_ab<JT>(Ab, lda, Bb, ldb, 0, As, Bs, r0, c0, wave);
  const int nt = K >> 6;
  for (int t = 0; t < nt; t++) {
    // Barrier t: lgkmcnt(0) -> all waves' ds_reads of buf[(t-1)&1] complete;
    // vmcnt(0) -> drains stage(t), issued one full compute-phase earlier.
    __syncthreads();
    if (t + 1 < nt)
      stage_ab<JT>(Ab, lda, Bb, ldb, (t + 1) << 6,
                   As + ((t + 1) & 1) * 8192, Bs + ((t + 1) & 1) * (JT * 2048),
                   r0, c0, wave);
    const s16x8* Av = (const s16x8*)(As + (t & 1) * 8192);
    const s16x8* Bv = (const s16x8*)(Bs + (t & 1) * (JT * 2048));
#pragma unroll
    for (int s = 0; s < 2; s++) {
      s16x8 af[4], bfr[JT];
#pragma unroll
      for (int u = 0; u < 4; u++) af[u] = Av[s * 512 + (wrow + u * 16 + rl) * 4 + q];
#pragma unroll
      for (int u = 0; u < JT; u++) bfr[u] = Bv[s * (JT * 128) + (wcol + u * 16 + rl) * 4 + q];
#pragma unroll
      for (int i = 0; i < 4; i++)
#pragma unroll
        for (int j = 0; j < JT; j++)
          acc[i][j] = mfma_bf16(af[i], bfr[j], acc[i][j]);
    }
  }
}

// EPI: 0 = Cb=bf16(acc+bias); 2 = Cf=acc+bias+res; 3 = Cb=bf16(relu(acc+bias))
template <int EPI, int JT>
__global__ __launch_bounds__(256) void gemm_bt(
    const unsigned short* __restrict__ A, int lda,
    const unsigned short* __restrict__ B, int ldb,
    const float* __restrict__ bias, const float* __restrict__ res,
    float* __restrict__ Cf, unsigned short* __restrict__ Cb, int ldc, int K)
{
  __shared__ __align__(16) unsigned short As[2 * 8192];        // 32KB (dbuf)
  __shared__ __align__(16) unsigned short Bs[2 * JT * 2048];   // JT=4:32KB JT=2:16KB
  int bm, bn;
  xcd_swz(gridDim.x, bn, bm);
  const int lane = threadIdx.x & 63, wave = threadIdx.x >> 6;
  const int wrow = (wave >> 1) * 64, wcol = (wave & 1) * 16 * JT;
  const int q = lane >> 4, rl = lane & 15;

  f32x4 acc[4][JT];
  f32x4 z = {0.f, 0.f, 0.f, 0.f};
#pragma unroll
  for (int i = 0; i < 4; i++)
#pragma unroll
    for (int j = 0; j < JT; j++) acc[i][j] = z;

  gemm_core_db<JT>(A + (size_t)bm * 128 * lda, lda,
                   B + (size_t)bn * (32 * JT) * ldb, ldb, K, As, Bs, acc);

#pragma unroll
  for (int i = 0; i < 4; i++) {
    int gm0 = bm * 128 + wrow + i * 16 + q * 4;
#pragma unroll
    for (int j = 0; j < JT; j++) {
      int gn = bn * (32 * JT) + wcol + j * 16 + rl;
      float bv = bias[gn];
#pragma unroll
      for (int r = 0; r < 4; r++) {
        size_t off = (size_t)(gm0 + r) * ldc + gn;
        float v = acc[i][j][r];
        if constexpr (EPI == 0) Cb[off] = f2b(v + bv);
        else if constexpr (EPI == 2) Cf[off] = v + bv + res[off];
        else Cb[off] = f2b(fmaxf(v + bv, 0.f));
      }
    }
  }
}

// ---------------------------------------------------------------------------
// FUSED QKV(self) + KV(cross) projection GEMM.  grid (40, 32):
//   bn 0..23  : A=Xb, W=Wq1|Wk1|Wv1, out QKVb  (bn 16..23 = V -> Vt1 direct)
//   bn 24..39 : A=Eb, W=Wk2|Wv2,     out KVb   (b2  8..15 = V -> Vt2 direct)
// V-range blocks emit V^T from the epilogue via the dead staging LDS.
// ---------------------------------------------------------------------------
__global__ __launch_bounds__(256) void gemm_qkvkv(
    const unsigned short* __restrict__ Xb, const unsigned short* __restrict__ Eb,
    const unsigned short* __restrict__ Wqkv1, const unsigned short* __restrict__ Wkv2,
    const float* __restrict__ bqkv, const float* __restrict__ bkv,
    unsigned short* __restrict__ QKVb, unsigned short* __restrict__ KVb,
    unsigned short* __restrict__ Vt1, unsigned short* __restrict__ Vt2)
{
  __shared__ __align__(16) unsigned short lds[32768];   // As dbuf 16384 | Bs dbuf 16384 (64KB)
  unsigned short* As = lds;
  unsigned short* Bs = lds + 16384;
  const int tid = threadIdx.x;
  int bm, bn;
  xcd_swz(gridDim.x, bn, bm);
  const int lane = tid & 63, wave = tid >> 6;
  const int wrow = (wave >> 1) * 64, wcol = (wave & 1) * 64;
  const int q = lane >> 4, rl = lane & 15;

  const unsigned short *A, *Bw;
  const float* bias;
  unsigned short *C, *Vt;
  int ldc, vbn;
  bool isV;
  if (bn < 24) {
    A = Xb; Bw = Wqkv1 + (size_t)bn * 128 * 1024; bias = bqkv + bn * 128;
    C = QKVb + bn * 128; ldc = 3072;
    isV = (bn >= 16); Vt = Vt1; vbn = bn - 16;
  } else {
    int b2 = bn - 24;
    A = Eb; Bw = Wkv2 + (size_t)b2 * 128 * 1024; bias = bkv + b2 * 128;
    C = KVb + b2 * 128; ldc = 2048;
    isV = (b2 >= 8); Vt = Vt2; vbn = b2 - 8;
  }

  f32x4 acc[4][4];
  f32x4 z = {0.f, 0.f, 0.f, 0.f};
#pragma unroll
  for (int i = 0; i < 4; i++)
#pragma unroll
    for (int j = 0; j < 4; j++) acc[i][j] = z;

  gemm_core_db<4>(A + (size_t)bm * 128 * 1024, 1024, Bw, 1024, 1024, As, Bs, acc);

  if (!isV) {
#pragma unroll
    for (int i = 0; i < 4; i++) {
      int lr0 = wrow + i * 16 + q * 4;
#pragma unroll
      for (int j = 0; j < 4; j++) {
        int lc = wcol + j * 16 + rl;
        float bv = bias[lc];
#pragma unroll
        for (int r = 0; r < 4; r++)
          C[(size_t)(bm * 128 + lr0 + r) * ldc + lc] = f2b(acc[i][j][r] + bv);
      }
    }
  } else {
    __syncthreads();   // dbuf loop has no trailing barrier: final ds_reads done
    // transpose via LDS: lds[lc*128 + (lr ^ ((lc&7)<<2))] = tile[lr][lc]
#pragma unroll
    for (int i = 0; i < 4; i++) {
      int lr0 = wrow + i * 16 + q * 4;
#pragma unroll
      for (int j = 0; j < 4; j++) {
        int lc = wcol + j * 16 + rl;
        float bv = bias[lc];
        int base = lc * 128, sw = (lc & 7) << 2;
#pragma unroll
        for (int r = 0; r < 4; r++)
          lds[base + ((lr0 + r) ^ sw)] = f2b(acc[i][j][r] + bv);
      }
    }
    __syncthreads();
    const int b = bm >> 3, s0 = (bm & 7) * 128;
#pragma unroll
    for (int it = 0; it < 16; it++) {
      int idx = it * 256 + tid;              // 4096 quads = 128 lc x 32 qa
      int lc = idx >> 5, qa = idx & 31;
      ushort4 v4 = *(const ushort4*)&lds[lc * 128 + ((qa ^ (lc & 7)) << 2)];
      int h = vbn * 2 + (lc >> 6), d = lc & 63;
      *(ushort4*)&Vt[(((size_t)b * 16 + h) * 64 + d) * 1024 + s0 + qa * 4] = v4;
    }
  }
}

// ---------------------------------------------------------------------------
// Flash building blocks.
// ---------------------------------------------------------------------------
__device__ __forceinline__ void stage_k(
    const unsigned short* src, int ldk, unsigned short* Kbuf,
    int r0, int c0, int wave)
{
#pragma unroll
  for (int kq = 0; kq < 2; kq++) {
    gload16(src + (size_t)r0 * ldk + kq * 32 + c0, Kbuf + kq * 4096 + wave * 512);
    gload16(src + (size_t)(r0 + 64) * ldk + kq * 32 + c0, Kbuf + kq * 4096 + wave * 512 + 2048);
  }
}

__device__ __forceinline__ void sblock_qk(
    const unsigned short* Qs, const unsigned short* Ks,
    int wrow, int wcol, int q, int rl, f32x4 (&acc)[4][4])
{
  const s16x8* Qv = (const s16x8*)Qs;
  const s16x8* Kv = (const s16x8*)Ks;
  f32x4 z = {0.f, 0.f, 0.f, 0.f};
#pragma unroll
  for (int i = 0; i < 4; i++)
#pragma unroll
    for (int j = 0; j < 4; j++) acc[i][j] = z;
#pragma unroll
  for (int kq = 0; kq < 2; kq++) {
    s16x8 af[4], bf[4];
#pragma unroll
    for (int t = 0; t < 4; t++) af[t] = Qv[kq * 512 + (wrow + t * 16 + rl) * 4 + q];
#pragma unroll
    for (int t = 0; t < 4; t++) bf[t] = Kv[kq * 512 + (wcol + t * 16 + rl) * 4 + q];
#pragma unroll
    for (int i = 0; i < 4; i++)
#pragma unroll
      for (int j = 0; j < 4; j++)
        acc[i][j] = mfma_bf16(af[i], bf[j], acc[i][j]);
  }
}

// V fragments directly from global (Vt is L2-resident).
__device__ __forceinline__ void load_vf(
    const unsigned short* Vbase, int c, int wc2, int q, int rl, s16x8 (&vf)[4][2])
{
#pragma unroll
  for (int ks = 0; ks < 4; ks++)
#pragma unroll
    for (int t = 0; t < 2; t++)
      vf[ks][t] = *(const s16x8*)(Vbase + (size_t)(wc2 + t * 16 + rl) * SS +
                                  c * 128 + ks * 32 + q * 8);
}

// P store into the swizzled standalone Ps tile ([4][128][32] u16, 16B-unit
// XOR swizzle: unit = (row*4 + u) ^ ((row>>1)&3)).
__device__ __forceinline__ void store_ps_swz(
    unsigned short* Ps, const f32x4 (&acc)[4][4], int wrow, int wcol, int q, int rl)
{
#pragma unroll
  for (int i = 0; i < 4; i++)
#pragma unroll
    for (int j = 0; j < 4; j++) {
      int col = wcol + j * 16 + rl;
      int ks = col >> 5, cc = col & 31;
#pragma unroll
      for (int r = 0; r < 4; r++) {
        int row = wrow + i * 16 + q * 4 + r;
        int unit = (row * 4 + (cc >> 3)) ^ ((row >> 1) & 3);
        Ps[ks * 4096 + unit * 8 + (cc & 7)] = f2b(acc[i][j][r]);
      }
    }
}

__device__ __forceinline__ void pv_swz(
    const unsigned short* Ps, const s16x8 (&vf)[4][2],
    int wrow, int q, int rl, f32x4 (&oacc)[4][2])
{
  const s16x8* Pv = (const s16x8*)Ps;
#pragma unroll
  for (int ks = 0; ks < 4; ks++) {
    s16x8 af[4];
#pragma unroll
    for (int t = 0; t < 4; t++) {
      int row = wrow + t * 16 + rl;
      af[t] = Pv[ks * 512 + ((row * 4 + q) ^ ((row >> 1) & 3))];
    }
#pragma unroll
    for (int i = 0; i < 4; i++)
#pragma unroll
      for (int jt = 0; jt < 2; jt++)
        oacc[i][jt] = mfma_bf16(af[i], vf[ks][jt], oacc[i][jt]);
  }
}

// ---------------------------------------------------------------------------
// NO-MAX flash attention, post-barrier staging + K double-buffer.
// 2 barriers/chunk; V direct-from-global.  LDS 80KB -> 2 blocks/CU.
// ---------------------------------------------------------------------------
__global__ __launch_bounds__(256, 2) void flash_sa(
    const unsigned short* __restrict__ Qg, int ldq,
    const unsigned short* __restrict__ Kg, int ldk,
    const unsigned short* __restrict__ Vt,     // [bh][64][1024]
    unsigned short* __restrict__ Og)           // [4096][1024]
{
  __shared__ __align__(16) unsigned short Qs[2 * 128 * 32];       // 16KB
  __shared__ __align__(16) unsigned short Ks[2][2 * 128 * 32];    // 32KB dbuf
  __shared__ __align__(16) unsigned short Ps[4 * 128 * 32];       // 32KB swizzled

  const int tid = threadIdx.x, wave = tid >> 6, lane = tid & 63;
  const int q = lane >> 4, rl = lane & 15;
  const int bh = blockIdx.y, b = bh >> 4, h = bh & 15;
  const int bm = (bh & 32) ? (7 - blockIdx.x) : blockIdx.x;   // causal balance
  const int wrow = (wave >> 1) * 64, wcol = (wave & 1) * 64;
  const int wc2 = (wave & 1) * 32;
  const int r0 = tid >> 2, c0 = (tid & 3) * 8;

  const unsigned short* Qbase = Qg + ((size_t)b * TT + bm * 128) * ldq + h * HD;
  const unsigned short* Kbase = Kg + (size_t)b * SS * ldk + h * HD;
  const unsigned short* Vbase = Vt + ((size_t)bh << 16);

#pragma unroll
  for (int kq = 0; kq < 2; kq++) {
    gload16(Qbase + (size_t)r0 * ldq + kq * 32 + c0, Qs + kq * 4096 + wave * 512);
    gload16(Qbase + (size_t)(r0 + 64) * ldq + kq * 32 + c0, Qs + kq * 4096 + wave * 512 + 2048);
  }
  stage_k(Kbase, ldk, Ks[0], r0, c0, wave);
  const int nch = bm + 1;

  float l_run[4][4];
  f32x4 oacc[4][2];
  f32x4 z = {0.f, 0.f, 0.f, 0.f};
#pragma unroll
  for (int i = 0; i < 4; i++) {
    oacc[i][0] = z; oacc[i][1] = z;
#pragma unroll
    for (int r = 0; r < 4; r++) l_run[i][r] = 0.f;
  }

  for (int c = 0; c < nch; c++) {
    __syncthreads();   // B_a: drains stage(c); syncs PV(c-1) -> K[c^1] & Ps free
    if (c + 1 < nch)
      stage_k(Kbase + (size_t)(c + 1) * 128 * ldk, ldk, Ks[(c + 1) & 1], r0, c0, wave);
    s16x8 vf[4][2];
    load_vf(Vbase, c, wc2, q, rl, vf);
    f32x4 acc[4][4];
    sblock_qk(Qs, Ks[c & 1], wrow, wcol, q, rl, acc);
    // P' = exp(s/8) (no max-sub; masked -> 0), accumulate wave-partial l
#pragma unroll
    for (int i = 0; i < 4; i++)
#pragma unroll
      for (int r = 0; r < 4; r++) {
#pragma unroll
        for (int j = 0; j < 4; j++) {
          float v = acc[i][j][r] * 0.125f;
          bool msk = (c == bm) && (wcol + j * 16 + rl) > (wrow + i * 16 + q * 4 + r);
          acc[i][j][r] = msk ? 0.f : __expf(v);
        }
        float s = acc[i][0][r] + acc[i][1][r] + acc[i][2][r] + acc[i][3][r];
#pragma unroll
        for (int off = 1; off < 16; off <<= 1) s += __shfl_xor(s, off);
        l_run[i][r] += s;
      }
    store_ps_swz(Ps, acc, wrow, wcol, q, rl);
    __syncthreads();   // B_b: Ps visible
    pv_swz(Ps, vf, wrow, q, rl, oacc);
  }
  __syncthreads();     // last PV reads of Ps done before reuse as red

  float* red = (float*)Ps;
  if (rl == 0) {
#pragma unroll
    for (int i = 0; i < 4; i++)
#pragma unroll
      for (int r = 0; r < 4; r++)
        red[(wave & 1) * 128 + wrow + i * 16 + q * 4 + r] = l_run[i][r];
  }
  __syncthreads();

#pragma unroll
  for (int i = 0; i < 4; i++) {
#pragma unroll
    for (int r = 0; r < 4; r++) {
      int row = wrow + i * 16 + q * 4 + r;
      float inv = 1.0f / (red[row] + red[128 + row]);
      int grow = bm * 128 + row;
#pragma unroll
      for (int jt = 0; jt < 2; jt++) {
        int col = h * HD + wc2 + jt * 16 + rl;
        Og[((size_t)b * TT + grow) * DD + col] = f2b(oacc[i][jt][r] * inv);
      }
    }
  }
}

// ---------------------------------------------------------------------------
// NO-MAX two-phase flash attention (cross-attn, fp32 P output).
// Phase A: post-barrier staged K dbuf -> 1 barrier/chunk.
// Phase B: 2 barriers/chunk; V direct; Pout via vectorized LDS readback.
// ---------------------------------------------------------------------------
__global__ __launch_bounds__(256, 2) void flash_ca(
    const unsigned short* __restrict__ Qg, int ldq,
    const unsigned short* __restrict__ Kg, int ldk,
    const unsigned short* __restrict__ Vt,     // [bh][64][1024]
    float* __restrict__ Pout,                  // [bh][1024][1024]
    unsigned short* __restrict__ Og)           // [4096][1024]
{
  __shared__ __align__(16) unsigned short Qs[2 * 128 * 32];
  __shared__ __align__(16) unsigned short Ks[2][2 * 128 * 32];
  __shared__ __align__(16) unsigned short Ps[4 * 128 * 32];

  const int tid = threadIdx.x, wave = tid >> 6, lane = tid & 63;
  const int q = lane >> 4, rl = lane & 15;
  const int bm = blockIdx.x, bh = blockIdx.y, b = bh >> 4, h = bh & 15;
  const int wrow = (wave >> 1) * 64, wcol = (wave & 1) * 64;
  const int wc2 = (wave & 1) * 32;
  const int r0 = tid >> 2, c0 = (tid & 3) * 8;

  const unsigned short* Qbase = Qg + ((size_t)b * TT + bm * 128) * ldq + h * HD;
  const unsigned short* Kbase = Kg + (size_t)b * SS * ldk + h * HD;
  const unsigned short* Vbase = Vt + ((size_t)bh << 16);

#pragma unroll
  for (int kq = 0; kq < 2; kq++) {
    gload16(Qbase + (size_t)r0 * ldq + kq * 32 + c0, Qs + kq * 4096 + wave * 512);
    gload16(Qbase + (size_t)(r0 + 64) * ldq + kq * 32 + c0, Qs + kq * 4096 + wave * 512 + 2048);
  }
  stage_k(Kbase, ldk, Ks[0], r0, c0, wave);

  float l_run[4][4];
#pragma unroll
  for (int i = 0; i < 4; i++)
#pragma unroll
    for (int r = 0; r < 4; r++) l_run[i][r] = 0.f;

  // ---------------- Phase A: denominators only (1 barrier/chunk) ----------
  for (int c = 0; c < 8; c++) {
    __syncthreads();   // drains stage(c) (a full chunk old for c>0)
    if (c < 7)
      stage_k(Kbase + (size_t)(c + 1) * 128 * ldk, ldk, Ks[(c + 1) & 1], r0, c0, wave);
    f32x4 acc[4][4];
    sblock_qk(Qs, Ks[c & 1], wrow, wcol, q, rl, acc);
#pragma unroll
    for (int i = 0; i < 4; i++)
#pragma unroll
      for (int r = 0; r < 4; r++) {
        float s = __expf(acc[i][0][r] * 0.125f) + __expf(acc[i][1][r] * 0.125f) +
                  __expf(acc[i][2][r] * 0.125f) + __expf(acc[i][3][r] * 0.125f);
#pragma unroll
        for (int off = 1; off < 16; off <<= 1) s += __shfl_xor(s, off);
        l_run[i][r] += s;
      }
  }
  float* red = (float*)Ps;   // Ps untouched in phase A
  if (rl == 0) {
#pragma unroll
    for (int i = 0; i < 4; i++)
#pragma unroll
      for (int r = 0; r < 4; r++)
        red[(wave & 1) * 128 + wrow + i * 16 + q * 4 + r] = l_run[i][r];
  }
  __syncthreads();
  float invl[4][4];
#pragma unroll
  for (int i = 0; i < 4; i++)
#pragma unroll
    for (int r = 0; r < 4; r++) {
      int row = wrow + i * 16 + q * 4 + r;
      invl[i][r] = 1.0f / (red[row] + red[128 + row]);
    }

  // ---------------- Phase B: P + PV (2 barriers/chunk) ----------
  f32x4 oacc[4][2];
  f32x4 z = {0.f, 0.f, 0.f, 0.f};
#pragma unroll
  for (int i = 0; i < 4; i++) { oacc[i][0] = z; oacc[i][1] = z; }
  stage_k(Kbase, ldk, Ks[0], r0, c0, wave);   // all waves past invl barrier

  for (int c = 0; c < 8; c++) {
    __syncthreads();   // B_a: drains stage(c); PV(c-1)/red reads done
    if (c < 7)
      stage_k(Kbase + (size_t)(c + 1) * 128 * ldk, ldk, Ks[(c + 1) & 1], r0, c0, wave);
    s16x8 vf[4][2];
    load_vf(Vbase, c, wc2, q, rl, vf);
    f32x4 acc[4][4];
    sblock_qk(Qs, Ks[c & 1], wrow, wcol, q, rl, acc);
#pragma unroll
    for (int i = 0; i < 4; i++)
#pragma unroll
      for (int j = 0; j < 4; j++)
#pragma unroll
        for (int r = 0; r < 4; r++)
          acc[i][j][r] = __expf(acc[i][j][r] * 0.125f) * invl[i][r];
    store_ps_swz(Ps, acc, wrow, wcol, q, rl);
    __syncthreads();   // B_b: Ps visible
    // P -> global, vectorized from LDS (bf16 -> 2x float4, 128B-coalesced)
#pragma unroll
    for (int it = 0; it < 8; it++) {
      int idx = it * 256 + tid;                  // [0,2048)
      int ks = idx >> 9, rw = (idx >> 2) & 127, u = idx & 3;
      s16x8 pv = ((const s16x8*)Ps)[ks * 512 + ((rw * 4 + u) ^ ((rw >> 1) & 3))];
      float4 lo = make_float4(b2f((unsigned short)pv[0]), b2f((unsigned short)pv[1]),
                              b2f((unsigned short)pv[2]), b2f((unsigned short)pv[3]));
      float4 hi = make_float4(b2f((unsigned short)pv[4]), b2f((unsigned short)pv[5]),
                              b2f((unsigned short)pv[6]), b2f((unsigned short)pv[7]));
      float* dst = Pout + ((size_t)bh << 20) + ((size_t)(bm * 128 + rw) << 10) +
                   c * 128 + ks * 32 + u * 8;
      ((float4*)dst)[0] = lo;
      ((float4*)dst)[1] = hi;
    }
    pv_swz(Ps, vf, wrow, q, rl, oacc);
  }

#pragma unroll
  for (int i = 0; i < 4; i++)
#pragma unroll
    for (int jt = 0; jt < 2; jt++)
#pragma unroll
      for (int r = 0; r < 4; r++) {
        int row = bm * 128 + wrow + i * 16 + q * 4 + r;
        int col = h * HD + wc2 + jt * 16 + rl;
        Og[((size_t)b * TT + row) * DD + col] = f2b(oacc[i][jt][r]);
      }
}

__global__ __launch_bounds__(256) void ln_k(
    const float* __restrict__ src, const float* __restrict__ g,
    const float* __restrict__ b, float* __restrict__ dstf,
    unsigned short* __restrict__ dstb)
{
  __shared__ float sh[10];
  const size_t row = blockIdx.x;
  const int tid = threadIdx.x;
  float4 v = ((const float4*)(src + (row << 10)))[tid];
  float s = v.x + v.y + v.z + v.w;
  float ss = v.x * v.x + v.y * v.y + v.z * v.z + v.w * v.w;
  for (int o = 32; o; o >>= 1) { s += __shfl_down(s, o); ss += __shfl_down(ss, o); }
  if ((tid & 63) == 0) { sh[tid >> 6] = s; sh[4 + (tid >> 6)] = ss; }
  __syncthreads();
  if (tid == 0) {
    sh[8] = sh[0] + sh[1] + sh[2] + sh[3];
    sh[9] = sh[4] + sh[5] + sh[6] + sh[7];
  }
  __syncthreads();
  const float mean = sh[8] * (1.0f / DD);
  const float var = sh[9] * (1.0f / DD) - mean * mean;
  const float inv = rsqrtf(var + 1e-5f);
  float4 gv = ((const float4*)g)[tid];
  float4 bv = ((const float4*)b)[tid];
  float4 y;
  y.x = (v.x - mean) * inv * gv.x + bv.x;
  y.y = (v.y - mean) * inv * gv.y + bv.y;
  y.z = (v.z - mean) * inv * gv.z + bv.z;
  y.w = (v.w - mean) * inv * gv.w + bv.w;
  if (dstf) ((float4*)(dstf + (row << 10)))[tid] = y;
  if (dstb) {
    ushort4 o = make_ushort4(f2b(y.x), f2b(y.y), f2b(y.z), f2b(y.w));
    ((ushort4*)(dstb + (row << 10)))[tid] = o;
  }
}

// ---------------------------------------------------------------------------
// Fused fp32 -> bf16 conversion of ALL inputs + bias packing in one launch.
// ---------------------------------------------------------------------------
struct CvtArgs {
  const float* src[12];
  unsigned short* dst[12];
  const float *bq, *bk, *bv, *bk2, *bv2;
  float *bqkv, *bkv;
};

__global__ __launch_bounds__(256) void cvt_all(CvtArgs a) {
  const int blk = blockIdx.x;
  if (blk >= 24576) {   // bias packing tail (20 blocks)
    int i = (blk - 24576) * 256 + threadIdx.x;
    if (i < 1024) a.bqkv[i] = a.bq[i];
    else if (i < 2048) a.bqkv[i] = a.bk[i - 1024];
    else if (i < 3072) a.bqkv[i] = a.bv[i - 2048];
    else if (i < 4096) a.bkv[i - 3072] = a.bk2[i - 3072];
    else if (i < 5120) a.bkv[i - 3072] = a.bv2[i - 4096 + 1024];
    return;
  }
  // f4 units: tgt(1M) enc(1M) 8x weights(256K) ff_w1(1M) ff_w2(1M)
  constexpr int st[13] = {0,       1048576, 2097152, 2359296, 2621440,
                          2883584, 3145728, 3407872, 3670016, 3932160,
                          4194304, 5242880, 6291456};
  int i = blk * 256 + threadIdx.x;
  int s = 0;
#pragma unroll
  for (int k = 1; k < 12; k++) s += (i >= st[k]) ? 1 : 0;
  int j = i - st[s];
  float4 v = ((const float4*)a.src[s])[j];
  ushort4 o = make_ushort4(f2b(v.x), f2b(v.y), f2b(v.z), f2b(v.w));
  ((ushort4*)a.dst[s])[j] = o;
}

// ---------------------------------------------------------------------------

extern "C" void kernel_launch(void* const* d_in, const int* in_sizes, int n_in,
                              void* d_out, int out_size, void* d_ws, size_t ws_size,
                              hipStream_t stream)
{
  const float* tgt = (const float*)d_in[0];
  const float* enc = (const float*)d_in[1];
  const float* sa_wq = (const float*)d_in[4];  const float* sa_bq = (const float*)d_in[5];
  const float* sa_wk = (const float*)d_in[6];  const float* sa_bk = (const float*)d_in[7];
  const float* sa_wv = (const float*)d_in[8];  const float* sa_bv = (const float*)d_in[9];
  const float* sa_wo = (const float*)d_in[10]; const float* sa_bo = (const float*)d_in[11];
  const float* ca_wq = (const float*)d_in[12]; const float* ca_bq = (const float*)d_in[13];
  const float* ca_wk = (const float*)d_in[14]; const float* ca_bk = (const float*)d_in[15];
  const float* ca_wv = (const float*)d_in[16]; const float* ca_bv = (const float*)d_in[17];
  const float* ca_wo = (const float*)d_in[18]; const float* ca_bo = (const float*)d_in[19];
  const float* ff_w1 = (const float*)d_in[20]; const float* ff_b1 = (const float*)d_in[21];
  const float* ff_w2 = (const float*)d_in[22]; const float* ff_b2 = (const float*)d_in[23];
  const float* ln1_g = (const float*)d_in[24]; const float* ln1_b = (const float*)d_in[25];
  const float* ln2_g = (const float*)d_in[26]; const float* ln2_b = (const float*)d_in[27];
  const float* ln3_g = (const float*)d_in[28]; const float* ln3_b = (const float*)d_in[29];

  float* out_tgt = (float*)d_out;
  float* out_attn = (float*)d_out + (size_t)MM * DD;

  char* w = (char*)d_ws;
  size_t off = 0;
  auto alloc = [&](size_t bytes) { void* p = w + off; off += (bytes + 255) & ~(size_t)255; return p; };
  unsigned short* Xb   = (unsigned short*)alloc((size_t)MM * DD * 2);
  unsigned short* Eb   = (unsigned short*)alloc((size_t)MM * DD * 2);
  unsigned short* Wq1  = (unsigned short*)alloc((size_t)DD * DD * 2);  // Wq1|Wk1|Wv1 contiguous
  unsigned short* Wk1  = (unsigned short*)alloc((size_t)DD * DD * 2);
  unsigned short* Wv1  = (unsigned short*)alloc((size_t)DD * DD * 2);
  unsigned short* Wo1  = (unsigned short*)alloc((size_t)DD * DD * 2);
  unsigned short* Wq2  = (unsigned short*)alloc((size_t)DD * DD * 2);
  unsigned short* Wk2  = (unsigned short*)alloc((size_t)DD * DD * 2);  // Wk2|Wv2 contiguous
  unsigned short* Wv2  = (unsigned short*)alloc((size_t)DD * DD * 2);
  unsigned short* Wo2  = (unsigned short*)alloc((size_t)DD * DD * 2);
  unsigned short* Wf1  = (unsigned short*)alloc((size_t)FFD * DD * 2);
  unsigned short* Wf2  = (unsigned short*)alloc((size_t)DD * FFD * 2);
  unsigned short* QKVb = (unsigned short*)alloc((size_t)MM * 3 * DD * 2); // [4096][3072]
  unsigned short* KVb  = (unsigned short*)alloc((size_t)MM * 2 * DD * 2); // [4096][2048]
  unsigned short* Qca  = (unsigned short*)alloc((size_t)MM * DD * 2);
  unsigned short* Vt1  = (unsigned short*)alloc((size_t)MM * DD * 2);
  unsigned short* Vt2  = (unsigned short*)alloc((size_t)MM * DD * 2);
  unsigned short* Ob   = (unsigned short*)alloc((size_t)MM * DD * 2);
  float*          res1 = (float*)alloc((size_t)MM * DD * 4);
  unsigned short* t1b  = (unsigned short*)alloc((size_t)MM * DD * 2);
  float*          res2 = (float*)alloc((size_t)MM * DD * 4);
  unsigned short* t2b  = (unsigned short*)alloc((size_t)MM * DD * 2);
  unsigned short* Fb   = (unsigned short*)alloc((size_t)MM * FFD * 2);
  float*          bqkv = (float*)alloc(3072 * 4);
  float*          bkv  = (float*)alloc(2048 * 4);

  CvtArgs ca;
  ca.src[0] = tgt;   ca.dst[0] = Xb;
  ca.src[1] = enc;   ca.dst[1] = Eb;
  ca.src[2] = sa_wq; ca.dst[2] = Wq1;
  ca.src[3] = sa_wk; ca.dst[3] = Wk1;
  ca.src[4] = sa_wv; ca.dst[4] = Wv1;
  ca.src[5] = sa_wo; ca.dst[5] = Wo1;
  ca.src[6] = ca_wq; ca.dst[6] = Wq2;
  ca.src[7] = ca_wk; ca.dst[7] = Wk2;
  ca.src[8] = ca_wv; ca.dst[8] = Wv2;
  ca.src[9] = ca_wo; ca.dst[9] = Wo2;
  ca.src[10] = ff_w1; ca.dst[10] = Wf1;
  ca.src[11] = ff_w2; ca.dst[11] = Wf2;
  ca.bq = sa_bq; ca.bk = sa_bk; ca.bv = sa_bv; ca.bk2 = ca_bk; ca.bv2 = ca_bv;
  ca.bqkv = bqkv; ca.bkv = bkv;

  cvt_all<<<24596, 256, 0, stream>>>(ca);

  const dim3 gPRJ(40, 32);           // fused QKV(24) + KV(16) column-tiles
  const dim3 gN64(16, 32);           // N=1024, 64-tiles (512 blocks)
  const dim3 gFF1(32, 32);           // N=4096, 128-tiles
  const dim3 gFl(8, 64);

  // ---- Projections (self QKV + cross KV, V^T emitted directly) ----
  gemm_qkvkv<<<gPRJ, 256, 0, stream>>>(Xb, Eb, Wq1, Wk2, bqkv, bkv,
                                       QKVb, KVb, Vt1, Vt2);

  // ---- Self-attention ----
  flash_sa<<<gFl, 256, 0, stream>>>(QKVb, 3 * DD, QKVb + DD, 3 * DD, Vt1, Ob);
  gemm_bt<2, 2><<<gN64, 256, 0, stream>>>(Ob, DD, Wo1, DD, sa_bo, tgt, res1, nullptr, DD, DD);
  ln_k<<<MM, 256, 0, stream>>>(res1, ln1_g, ln1_b, res1, t1b);

  // ---- Cross-attention ----
  gemm_bt<0, 2><<<gN64, 256, 0, stream>>>(t1b, DD, Wq2, DD, ca_bq, nullptr, nullptr, Qca, DD, DD);
  flash_ca<<<gFl, 256, 0, stream>>>(Qca, DD, KVb, 2 * DD, Vt2, out_attn, Ob);
  gemm_bt<2, 2><<<gN64, 256, 0, stream>>>(Ob, DD, Wo2, DD, ca_bo, res1, res2, nullptr, DD, DD);
  ln_k<<<MM, 256, 0, stream>>>(res2, ln2_g, ln2_b, res2, t2b);

  // ---- Feed-forward ----
  gemm_bt<3, 4><<<gFF1, 256, 0, stream>>>(t2b, DD, Wf1, DD, ff_b1, nullptr, nullptr, Fb, FFD, DD);
  gemm_bt<2, 2><<<gN64, 256, 0, stream>>>(Fb, FFD, Wf2, FFD, ff_b2, res2, res1, nullptr, DD, FFD);
  ln_k<<<MM, 256, 0, stream>>>(res1, ln3_g, ln3_b, out_tgt, nullptr);
}